// Round 1
// baseline (1275.484 us; speedup 1.0000x reference)
//
#include <hip/hip_runtime.h>
#include <math.h>

#define NB 8
#define NN 4096   // pixels per batch
#define NC 128    // channels

// ---------------------------------------------------------------------------
// K1: projections f,g,h.  out[r][d] = sum_c x[r][c]*W[c][d] + b[d]
// rows = 32768, tile 32 rows x 128 cols, block 256 = (tx:32 cols4, ty:8 rows4)
// ---------------------------------------------------------------------------
__global__ __launch_bounds__(256) void k_proj(
    const float* __restrict__ x,
    const float* __restrict__ Wf, const float* __restrict__ bf,
    const float* __restrict__ Wg, const float* __restrict__ bg,
    const float* __restrict__ Wh, const float* __restrict__ bh,
    float* __restrict__ f, float* __restrict__ g, float* __restrict__ h)
{
    const float* W; const float* bias; float* out;
    if (blockIdx.z == 0)      { W = Wf; bias = bf; out = f; }
    else if (blockIdx.z == 1) { W = Wg; bias = bg; out = g; }
    else                      { W = Wh; bias = bh; out = h; }

    __shared__ __align__(16) float ast[32 * 32];    // [c][r]
    __shared__ __align__(16) float bs [32 * 128];   // [c][d]

    const int tid = threadIdx.x;
    const int tx = tid & 31, ty = tid >> 5;
    const int r0 = blockIdx.x * 32;

    float acc[4][4] = {};

    for (int cc = 0; cc < 128; cc += 32) {
        __syncthreads();
        {   // stage A (transpose): 1024 floats, 1 float4/thread
            int r = tid >> 3, c4 = tid & 7;
            float4 v = *(const float4*)&x[(size_t)(r0 + r) * NC + cc + c4 * 4];
            ast[(c4 * 4 + 0) * 32 + r] = v.x;
            ast[(c4 * 4 + 1) * 32 + r] = v.y;
            ast[(c4 * 4 + 2) * 32 + r] = v.z;
            ast[(c4 * 4 + 3) * 32 + r] = v.w;
        }
        // stage B (direct): 4096 floats, 4 float4/thread
        #pragma unroll
        for (int i = 0; i < 4; i++) {
            int idx = tid + i * 256;
            *(float4*)&bs[idx * 4] = *(const float4*)&W[(size_t)cc * 128 + idx * 4];
        }
        __syncthreads();
        #pragma unroll
        for (int c = 0; c < 32; c++) {
            float4 a  = *(const float4*)&ast[c * 32 + ty * 4];
            float4 b4 = *(const float4*)&bs [c * 128 + tx * 4];
            acc[0][0] += a.x * b4.x; acc[0][1] += a.x * b4.y; acc[0][2] += a.x * b4.z; acc[0][3] += a.x * b4.w;
            acc[1][0] += a.y * b4.x; acc[1][1] += a.y * b4.y; acc[1][2] += a.y * b4.z; acc[1][3] += a.y * b4.w;
            acc[2][0] += a.z * b4.x; acc[2][1] += a.z * b4.y; acc[2][2] += a.z * b4.z; acc[2][3] += a.z * b4.w;
            acc[3][0] += a.w * b4.x; acc[3][1] += a.w * b4.y; acc[3][2] += a.w * b4.z; acc[3][3] += a.w * b4.w;
        }
    }

    float4 bb = *(const float4*)&bias[tx * 4];
    #pragma unroll
    for (int i = 0; i < 4; i++) {
        float4 r;
        r.x = acc[i][0] + bb.x; r.y = acc[i][1] + bb.y;
        r.z = acc[i][2] + bb.z; r.w = acc[i][3] + bb.w;
        *(float4*)&out[(size_t)(r0 + ty * 4 + i) * NC + tx * 4] = r;
    }
}

// ---------------------------------------------------------------------------
// K2: scores strip.  S[b][rl][m] = sum_c fx[b][s_off+rl][c] * gx[b][m][c]
// tile 64x64, block 256 (tx:16, ty:16), 4x4/thread, K=128 in chunks of 32
// ---------------------------------------------------------------------------
__global__ __launch_bounds__(256) void k_scores(
    const float* __restrict__ fx, const float* __restrict__ gx,
    float* __restrict__ S, int s_off, int SR)
{
    const int b  = blockIdx.z;
    const int m0 = blockIdx.x * 64;
    const int nl0 = blockIdx.y * 64;
    const int ng0 = s_off + nl0;

    __shared__ __align__(16) float ast[32 * 64];  // [c][n]
    __shared__ __align__(16) float bst[32 * 64];  // [c][m]

    const int tid = threadIdx.x;
    const int tx = tid & 15, ty = tid >> 4;
    const float* fB = fx + (size_t)b * NN * NC;
    const float* gB = gx + (size_t)b * NN * NC;

    float acc[4][4] = {};

    for (int cc = 0; cc < 128; cc += 32) {
        __syncthreads();
        #pragma unroll
        for (int i = 0; i < 2; i++) {
            int idx = tid + i * 256;            // 0..511
            int r = idx >> 3, c4 = idx & 7;
            float4 v = *(const float4*)&fB[(size_t)(ng0 + r) * NC + cc + c4 * 4];
            ast[(c4 * 4 + 0) * 64 + r] = v.x;
            ast[(c4 * 4 + 1) * 64 + r] = v.y;
            ast[(c4 * 4 + 2) * 64 + r] = v.z;
            ast[(c4 * 4 + 3) * 64 + r] = v.w;
            float4 w = *(const float4*)&gB[(size_t)(m0 + r) * NC + cc + c4 * 4];
            bst[(c4 * 4 + 0) * 64 + r] = w.x;
            bst[(c4 * 4 + 1) * 64 + r] = w.y;
            bst[(c4 * 4 + 2) * 64 + r] = w.z;
            bst[(c4 * 4 + 3) * 64 + r] = w.w;
        }
        __syncthreads();
        #pragma unroll
        for (int c = 0; c < 32; c++) {
            float4 a  = *(const float4*)&ast[c * 64 + ty * 4];
            float4 b4 = *(const float4*)&bst[c * 64 + tx * 4];
            acc[0][0] += a.x * b4.x; acc[0][1] += a.x * b4.y; acc[0][2] += a.x * b4.z; acc[0][3] += a.x * b4.w;
            acc[1][0] += a.y * b4.x; acc[1][1] += a.y * b4.y; acc[1][2] += a.y * b4.z; acc[1][3] += a.y * b4.w;
            acc[2][0] += a.z * b4.x; acc[2][1] += a.z * b4.y; acc[2][2] += a.z * b4.z; acc[2][3] += a.z * b4.w;
            acc[3][0] += a.w * b4.x; acc[3][1] += a.w * b4.y; acc[3][2] += a.w * b4.z; acc[3][3] += a.w * b4.w;
        }
    }

    #pragma unroll
    for (int i = 0; i < 4; i++) {
        float4 r;
        r.x = acc[i][0]; r.y = acc[i][1]; r.z = acc[i][2]; r.w = acc[i][3];
        *(float4*)&S[((size_t)b * SR + nl0 + ty * 4 + i) * NN + m0 + tx * 4] = r;
    }
}

// ---------------------------------------------------------------------------
// K3: row softmax stats (max, 1/sum) per strip row. One block per row.
// ---------------------------------------------------------------------------
__global__ __launch_bounds__(256) void k_stats(
    const float* __restrict__ S, float* __restrict__ rmax, float* __restrict__ rsum,
    int s_off, int SR)
{
    const int row = blockIdx.x;           // 0 .. 8*SR-1 == b*SR + rl
    const int b = row / SR, rl = row % SR;
    const float* p = S + (size_t)row * NN;
    const int t = threadIdx.x;

    float4 v[4];
    float mx = -INFINITY;
    #pragma unroll
    for (int k = 0; k < 4; k++) {
        v[k] = *(const float4*)&p[k * 1024 + t * 4];
        mx = fmaxf(mx, fmaxf(fmaxf(v[k].x, v[k].y), fmaxf(v[k].z, v[k].w)));
    }

    __shared__ float red[256];
    red[t] = mx;
    __syncthreads();
    for (int s = 128; s > 0; s >>= 1) {
        if (t < s) red[t] = fmaxf(red[t], red[t + s]);
        __syncthreads();
    }
    mx = red[0];
    __syncthreads();

    float sum = 0.f;
    #pragma unroll
    for (int k = 0; k < 4; k++) {
        sum += __expf(v[k].x - mx) + __expf(v[k].y - mx)
             + __expf(v[k].z - mx) + __expf(v[k].w - mx);
    }
    red[t] = sum;
    __syncthreads();
    for (int s = 128; s > 0; s >>= 1) {
        if (t < s) red[t] += red[t + s];
        __syncthreads();
    }
    if (t == 0) {
        rmax[b * NN + s_off + rl] = mx;
        rsum[b * NN + s_off + rl] = 1.0f / red[0];
    }
}

// ---------------------------------------------------------------------------
// K4: O[b][c][m] (+)= sum_{n in strip} hx[b][n][c] * alpha[b][n][m]
// block tile: 128c x 64m, block 256 (tx:16 m4, ty:16 c8), K chunks of 32
// ---------------------------------------------------------------------------
__global__ __launch_bounds__(256) void k_attnout(
    const float* __restrict__ hx, const float* __restrict__ S,
    const float* __restrict__ rmax, const float* __restrict__ rsum,
    float* __restrict__ o, int s_off, int SR, int accumulate)
{
    const int b  = blockIdx.y;
    const int m0 = blockIdx.x * 64;

    __shared__ __align__(16) float hs[32 * 128];  // [n][c]
    __shared__ __align__(16) float as[32 * 64];   // [n][m]

    const int tid = threadIdx.x;
    const int tx = tid & 15, ty = tid >> 4;
    const float* hB  = hx + ((size_t)b * NN + s_off) * NC;
    const float* SB  = S + (size_t)b * SR * NN;
    const float* mxp = rmax + b * NN + s_off;
    const float* isp = rsum + b * NN + s_off;

    float acc[8][4] = {};

    for (int nc = 0; nc < SR; nc += 32) {
        __syncthreads();
        #pragma unroll
        for (int i = 0; i < 4; i++) {   // hs: 4096 floats direct
            int idx = tid + i * 256;
            *(float4*)&hs[idx * 4] = *(const float4*)&hB[(size_t)nc * NC + idx * 4];
        }
        #pragma unroll
        for (int i = 0; i < 2; i++) {   // as: 2048 floats with exp transform
            int idx = tid + i * 256;
            int n = idx >> 4, m4 = idx & 15;
            float4 v = *(const float4*)&SB[(size_t)(nc + n) * NN + m0 + m4 * 4];
            float mxv = mxp[nc + n], isv = isp[nc + n];
            v.x = __expf(v.x - mxv) * isv;
            v.y = __expf(v.y - mxv) * isv;
            v.z = __expf(v.z - mxv) * isv;
            v.w = __expf(v.w - mxv) * isv;
            *(float4*)&as[n * 64 + m4 * 4] = v;
        }
        __syncthreads();
        #pragma unroll
        for (int n = 0; n < 32; n++) {
            float4 b0  = *(const float4*)&as[n * 64 + tx * 4];
            float4 alo = *(const float4*)&hs[n * 128 + ty * 8];
            float4 ahi = *(const float4*)&hs[n * 128 + ty * 8 + 4];
            acc[0][0] += alo.x * b0.x; acc[0][1] += alo.x * b0.y; acc[0][2] += alo.x * b0.z; acc[0][3] += alo.x * b0.w;
            acc[1][0] += alo.y * b0.x; acc[1][1] += alo.y * b0.y; acc[1][2] += alo.y * b0.z; acc[1][3] += alo.y * b0.w;
            acc[2][0] += alo.z * b0.x; acc[2][1] += alo.z * b0.y; acc[2][2] += alo.z * b0.z; acc[2][3] += alo.z * b0.w;
            acc[3][0] += alo.w * b0.x; acc[3][1] += alo.w * b0.y; acc[3][2] += alo.w * b0.z; acc[3][3] += alo.w * b0.w;
            acc[4][0] += ahi.x * b0.x; acc[4][1] += ahi.x * b0.y; acc[4][2] += ahi.x * b0.z; acc[4][3] += ahi.x * b0.w;
            acc[5][0] += ahi.y * b0.x; acc[5][1] += ahi.y * b0.y; acc[5][2] += ahi.y * b0.z; acc[5][3] += ahi.y * b0.w;
            acc[6][0] += ahi.z * b0.x; acc[6][1] += ahi.z * b0.y; acc[6][2] += ahi.z * b0.z; acc[6][3] += ahi.z * b0.w;
            acc[7][0] += ahi.w * b0.x; acc[7][1] += ahi.w * b0.y; acc[7][2] += ahi.w * b0.z; acc[7][3] += ahi.w * b0.w;
        }
    }

    #pragma unroll
    for (int i = 0; i < 8; i++) {
        float* p = o + ((size_t)b * NC + ty * 8 + i) * NN + m0 + tx * 4;
        float4 r;
        r.x = acc[i][0]; r.y = acc[i][1]; r.z = acc[i][2]; r.w = acc[i][3];
        if (accumulate) {
            float4 old = *(const float4*)p;
            r.x += old.x; r.y += old.y; r.z += old.z; r.w += old.w;
        }
        *(float4*)p = r;
    }
}

// ---------------------------------------------------------------------------
// K5: final projection, IN PLACE on d_out viewed as [32768][128].
// Each block owns 32 rows: reads all its inputs before writing (safe).
// ---------------------------------------------------------------------------
__global__ __launch_bounds__(256) void k_vproj(
    float* __restrict__ o, const float* __restrict__ Wv, const float* __restrict__ bv)
{
    __shared__ __align__(16) float ast[32 * 32];    // [c][r]
    __shared__ __align__(16) float bs [32 * 128];   // [c][d]

    const int tid = threadIdx.x;
    const int tx = tid & 31, ty = tid >> 5;
    const int r0 = blockIdx.x * 32;

    float acc[4][4] = {};

    for (int cc = 0; cc < 128; cc += 32) {
        __syncthreads();
        {
            int r = tid >> 3, c4 = tid & 7;
            float4 v = *(const float4*)&o[(size_t)(r0 + r) * NC + cc + c4 * 4];
            ast[(c4 * 4 + 0) * 32 + r] = v.x;
            ast[(c4 * 4 + 1) * 32 + r] = v.y;
            ast[(c4 * 4 + 2) * 32 + r] = v.z;
            ast[(c4 * 4 + 3) * 32 + r] = v.w;
        }
        #pragma unroll
        for (int i = 0; i < 4; i++) {
            int idx = tid + i * 256;
            *(float4*)&bs[idx * 4] = *(const float4*)&Wv[(size_t)cc * 128 + idx * 4];
        }
        __syncthreads();
        #pragma unroll
        for (int c = 0; c < 32; c++) {
            float4 a  = *(const float4*)&ast[c * 32 + ty * 4];
            float4 b4 = *(const float4*)&bs [c * 128 + tx * 4];
            acc[0][0] += a.x * b4.x; acc[0][1] += a.x * b4.y; acc[0][2] += a.x * b4.z; acc[0][3] += a.x * b4.w;
            acc[1][0] += a.y * b4.x; acc[1][1] += a.y * b4.y; acc[1][2] += a.y * b4.z; acc[1][3] += a.y * b4.w;
            acc[2][0] += a.z * b4.x; acc[2][1] += a.z * b4.y; acc[2][2] += a.z * b4.z; acc[2][3] += a.z * b4.w;
            acc[3][0] += a.w * b4.x; acc[3][1] += a.w * b4.y; acc[3][2] += a.w * b4.z; acc[3][3] += a.w * b4.w;
        }
    }
    // all reads of this block's rows are complete; safe to overwrite in place
    float4 bb = *(const float4*)&bv[tx * 4];
    #pragma unroll
    for (int i = 0; i < 4; i++) {
        float4 r;
        r.x = acc[i][0] + bb.x; r.y = acc[i][1] + bb.y;
        r.z = acc[i][2] + bb.z; r.w = acc[i][3] + bb.w;
        *(float4*)&o[(size_t)(r0 + ty * 4 + i) * NC + tx * 4] = r;
    }
}

// ---------------------------------------------------------------------------
extern "C" void kernel_launch(void* const* d_in, const int* in_sizes, int n_in,
                              void* d_out, int out_size, void* d_ws, size_t ws_size,
                              hipStream_t stream)
{
    const float* x  = (const float*)d_in[0];
    const float* Wf = (const float*)d_in[1];
    const float* bf = (const float*)d_in[2];
    const float* Wg = (const float*)d_in[3];
    const float* bg = (const float*)d_in[4];
    const float* Wh = (const float*)d_in[5];
    const float* bh = (const float*)d_in[6];
    const float* Wv = (const float*)d_in[7];
    const float* bv = (const float*)d_in[8];
    float* out = (float*)d_out;

    // workspace layout
    float* fx   = (float*)d_ws;                       // 32768*128
    float* gx   = fx + (size_t)NB * NN * NC;
    float* hx   = gx + (size_t)NB * NN * NC;
    float* rmax = hx + (size_t)NB * NN * NC;          // 32768
    float* rsum = rmax + (size_t)NB * NN;             // 32768
    float* S    = rsum + (size_t)NB * NN;             // 8*SR*4096

    size_t used = (size_t)((char*)S - (char*)d_ws);
    size_t avail = (ws_size > used) ? (ws_size - used) : 0;
    int SR = 512;                                     // strip rows (power of 2)
    while (SR > 64 && (size_t)NB * SR * NN * 4 > avail) SR >>= 1;

    // 1) projections
    k_proj<<<dim3(1024, 1, 3), 256, 0, stream>>>(x, Wf, bf, Wg, bg, Wh, bh, fx, gx, hx);

    // 2) per-strip: scores -> stats -> accumulate O (staged in d_out as [B,C,N])
    const int nstrips = NN / SR;
    for (int s = 0; s < nstrips; s++) {
        int s_off = s * SR;
        k_scores<<<dim3(64, SR / 64, NB), 256, 0, stream>>>(fx, gx, S, s_off, SR);
        k_stats <<<dim3(NB * SR), 256, 0, stream>>>(S, rmax, rsum, s_off, SR);
        k_attnout<<<dim3(64, NB), 256, 0, stream>>>(hx, S, rmax, rsum, out, s_off, SR, s > 0);
    }

    // 3) final projection in place (implements the [B,C,N]->[B,N,C] flat reshape)
    k_vproj<<<dim3(1024), 256, 0, stream>>>(out, Wv, bv);
}

// Round 2
// 618.554 us; speedup vs baseline: 2.0620x; 2.0620x over previous
//
#include <hip/hip_runtime.h>
#include <math.h>

#define NB 8
#define NN 4096   // pixels per batch
#define NC 128    // channels

typedef __attribute__((ext_vector_type(8))) short bf16x8;
typedef __attribute__((ext_vector_type(4))) float f32x4;

static __device__ __forceinline__ unsigned short f2bf(float f) {
    unsigned u = __builtin_bit_cast(unsigned, f);
    return (unsigned short)((u + 0x7FFFu + ((u >> 16) & 1u)) >> 16);
}

// ---------------------------------------------------------------------------
// K1: projections f,g,h (fp32 compute, bf16 outputs).
// f,g: [B*N][C] bf16 row-major.  h: TRANSPOSED ht[B][C][N] bf16.
// grid (1024,1,3) block 256 = (tx:32 cols4, ty:8 rows4)
// ---------------------------------------------------------------------------
__global__ __launch_bounds__(256) void k_proj(
    const float* __restrict__ x,
    const float* __restrict__ Wf, const float* __restrict__ bf,
    const float* __restrict__ Wg, const float* __restrict__ bg,
    const float* __restrict__ Wh, const float* __restrict__ bh,
    unsigned short* __restrict__ fb, unsigned short* __restrict__ gb,
    unsigned short* __restrict__ htb)
{
    const float* W; const float* bias;
    if (blockIdx.z == 0)      { W = Wf; bias = bf; }
    else if (blockIdx.z == 1) { W = Wg; bias = bg; }
    else                      { W = Wh; bias = bh; }

    __shared__ __align__(16) float ast[32 * 32];    // [c][r]
    __shared__ __align__(16) float bs [32 * 128];   // [c][d]

    const int tid = threadIdx.x;
    const int tx = tid & 31, ty = tid >> 5;
    const int r0 = blockIdx.x * 32;

    float acc[4][4] = {};

    for (int cc = 0; cc < 128; cc += 32) {
        __syncthreads();
        {   // stage A (transpose): 1024 floats
            int r = tid >> 3, c4 = tid & 7;
            float4 v = *(const float4*)&x[(size_t)(r0 + r) * NC + cc + c4 * 4];
            ast[(c4 * 4 + 0) * 32 + r] = v.x;
            ast[(c4 * 4 + 1) * 32 + r] = v.y;
            ast[(c4 * 4 + 2) * 32 + r] = v.z;
            ast[(c4 * 4 + 3) * 32 + r] = v.w;
        }
        #pragma unroll
        for (int i = 0; i < 4; i++) {
            int idx = tid + i * 256;
            *(float4*)&bs[idx * 4] = *(const float4*)&W[(size_t)cc * 128 + idx * 4];
        }
        __syncthreads();
        #pragma unroll
        for (int c = 0; c < 32; c++) {
            float4 a  = *(const float4*)&ast[c * 32 + ty * 4];
            float4 b4 = *(const float4*)&bs [c * 128 + tx * 4];
            acc[0][0] += a.x * b4.x; acc[0][1] += a.x * b4.y; acc[0][2] += a.x * b4.z; acc[0][3] += a.x * b4.w;
            acc[1][0] += a.y * b4.x; acc[1][1] += a.y * b4.y; acc[1][2] += a.y * b4.z; acc[1][3] += a.y * b4.w;
            acc[2][0] += a.z * b4.x; acc[2][1] += a.z * b4.y; acc[2][2] += a.z * b4.z; acc[2][3] += a.z * b4.w;
            acc[3][0] += a.w * b4.x; acc[3][1] += a.w * b4.y; acc[3][2] += a.w * b4.z; acc[3][3] += a.w * b4.w;
        }
    }

    float4 bb = *(const float4*)&bias[tx * 4];
    float bbv[4] = { bb.x, bb.y, bb.z, bb.w };

    if (blockIdx.z < 2) {
        unsigned short* out = (blockIdx.z == 0) ? fb : gb;
        #pragma unroll
        for (int i = 0; i < 4; i++) {
            ushort4 v;
            v.x = f2bf(acc[i][0] + bbv[0]);
            v.y = f2bf(acc[i][1] + bbv[1]);
            v.z = f2bf(acc[i][2] + bbv[2]);
            v.w = f2bf(acc[i][3] + bbv[3]);
            *(ushort4*)&out[(size_t)(r0 + ty * 4 + i) * NC + tx * 4] = v;
        }
    } else {
        // h transposed: ht[b][c][n]
        const int b = r0 >> 12;
        const int n0 = (r0 & (NN - 1)) + ty * 4;
        #pragma unroll
        for (int j = 0; j < 4; j++) {
            int c = tx * 4 + j;
            ushort4 v;
            v.x = f2bf(acc[0][j] + bbv[j]);
            v.y = f2bf(acc[1][j] + bbv[j]);
            v.z = f2bf(acc[2][j] + bbv[j]);
            v.w = f2bf(acc[3][j] + bbv[j]);
            *(ushort4*)&htb[((size_t)b * NC + c) * NN + n0] = v;
        }
    }
}

// ---------------------------------------------------------------------------
// K2: row softmax stats via MFMA recompute. Block 256 = 4 waves.
// Wave w owns rows [blockIdx.x*64 + w*16, +16). Loops all 4096 m in 16-tiles.
// stat[b][n] = (rowmax, 1/rowsum) as float2.
// ---------------------------------------------------------------------------
__global__ __launch_bounds__(256) void k_stats(
    const unsigned short* __restrict__ fb, const unsigned short* __restrict__ gb,
    float2* __restrict__ stat)
{
    const int b = blockIdx.y;
    const int w = threadIdx.x >> 6;
    const int l = threadIdx.x & 63;
    const int lr = l & 15, g = l >> 4;
    const int nbase = blockIdx.x * 64 + w * 16;

    // hoist A fragments (fx rows fixed for this wave)
    const unsigned short* fRow = fb + ((size_t)b * NN + nbase + lr) * NC;
    bf16x8 afr[4];
    #pragma unroll
    for (int kc = 0; kc < 4; kc++)
        afr[kc] = *(const bf16x8*)&fRow[kc * 32 + g * 8];

    const unsigned short* gB = gb + (size_t)b * NN * NC;

    float mrun[4] = { -INFINITY, -INFINITY, -INFINITY, -INFINITY };
    float srun[4] = { 0.f, 0.f, 0.f, 0.f };

    for (int mt = 0; mt < NN / 16; mt++) {
        const unsigned short* gRow = gB + (size_t)(mt * 16 + lr) * NC;
        f32x4 S = { 0.f, 0.f, 0.f, 0.f };
        #pragma unroll
        for (int kc = 0; kc < 4; kc++) {
            bf16x8 bfr = *(const bf16x8*)&gRow[kc * 32 + g * 8];
            S = __builtin_amdgcn_mfma_f32_16x16x32_bf16(afr[kc], bfr, S, 0, 0, 0);
        }
        #pragma unroll
        for (int r = 0; r < 4; r++) {
            float v = S[r];
            float nm = fmaxf(mrun[r], v);
            srun[r] = srun[r] * __expf(mrun[r] - nm) + __expf(v - nm);
            mrun[r] = nm;
        }
    }

    // reduce (max,sum) across the 16 lanes of each row group
    #pragma unroll
    for (int d = 1; d < 16; d <<= 1) {
        #pragma unroll
        for (int r = 0; r < 4; r++) {
            float mo = __shfl_xor(mrun[r], d, 64);
            float so = __shfl_xor(srun[r], d, 64);
            float nm = fmaxf(mrun[r], mo);
            srun[r] = srun[r] * __expf(mrun[r] - nm) + so * __expf(mo - nm);
            mrun[r] = nm;
        }
    }

    if (lr == 0) {
        #pragma unroll
        for (int r = 0; r < 4; r++) {
            int n = nbase + 4 * g + r;
            stat[(size_t)b * NN + n] = make_float2(mrun[r], 1.0f / srun[r]);
        }
    }
}

// ---------------------------------------------------------------------------
// K3: O[b][c][m] = sum_n ht[b][c][n] * alpha[b][n][m], alpha recomputed.
// Block 512 = 8 waves, m-tile 64, n-chunk 32, P double-buffered in LDS.
// S-phase: wave w computes S-tile rows nsub=(w&1)*16, cols msub=(w>>1)*16.
// O-phase: wave w owns c-range [w*16, +16), all 4 m-subtiles.
// ---------------------------------------------------------------------------
__global__ __launch_bounds__(512) void k_out(
    const unsigned short* __restrict__ fb, const unsigned short* __restrict__ gb,
    const unsigned short* __restrict__ htb, const float2* __restrict__ stat,
    float* __restrict__ o)
{
    const int b = blockIdx.y;
    const int m_blk = blockIdx.x * 64;
    const int tid = threadIdx.x;
    const int w = tid >> 6, l = tid & 63;
    const int lr = l & 15, g = l >> 4;
    const int nsub = (w & 1) * 16;
    const int msub = (w >> 1) * 16;

    // P_t[m][n] bf16, 64 rows x 32 cols, XOR-swizzled, double buffered
    __shared__ __align__(16) unsigned char Pbuf[2 * 64 * 32 * 2];

    // hoist gx B-fragments (cols fixed per wave)
    const unsigned short* gRow = gb + ((size_t)b * NN + m_blk + msub + lr) * NC;
    bf16x8 gfr[4];
    #pragma unroll
    for (int kc = 0; kc < 4; kc++)
        gfr[kc] = *(const bf16x8*)&gRow[kc * 32 + g * 8];

    const unsigned short* fB = fb + (size_t)b * NN * NC;
    const unsigned short* hC = htb + ((size_t)b * NC + w * 16 + lr) * NN;  // A row c for O phase
    const float2* st = stat + (size_t)b * NN;

    f32x4 acc[4] = { {0,0,0,0}, {0,0,0,0}, {0,0,0,0}, {0,0,0,0} };

    const int m_l = msub + lr;                  // P row this lane writes
    const unsigned wr_addr = (unsigned)((m_l * 64 + (nsub + 4 * g) * 2) ^ ((m_l & 7) << 4));

    for (int nc = 0; nc < NN / 32; nc++) {
        const int n0 = nc * 32;
        // ---- S tile: rows n0+nsub+lr (A), cols m_blk+msub+lr (B hoisted)
        const unsigned short* fRow = fB + (size_t)(n0 + nsub + lr) * NC;
        f32x4 S = { 0.f, 0.f, 0.f, 0.f };
        #pragma unroll
        for (int kc = 0; kc < 4; kc++) {
            bf16x8 afr = *(const bf16x8*)&fRow[kc * 32 + g * 8];
            S = __builtin_amdgcn_mfma_f32_16x16x32_bf16(afr, gfr[kc], S, 0, 0, 0);
        }
        // ---- alpha = exp(S - rmax) * rinv  -> bf16
        ushort4 pv;
        {
            int n = n0 + nsub + 4 * g;
            float2 s0 = st[n + 0], s1 = st[n + 1], s2 = st[n + 2], s3 = st[n + 3];
            pv.x = f2bf(__expf(S[0] - s0.x) * s0.y);
            pv.y = f2bf(__expf(S[1] - s1.x) * s1.y);
            pv.z = f2bf(__expf(S[2] - s2.x) * s2.y);
            pv.w = f2bf(__expf(S[3] - s3.x) * s3.y);
        }
        unsigned char* base = Pbuf + (nc & 1) * (64 * 32 * 2);
        *(ushort4*)(base + wr_addr) = pv;      // 8B write, conflict-light (swizzled)
        __syncthreads();
        // ---- O accumulate: A = ht[c][n-chunk] (global, contiguous 16B), B = P_t from LDS
        bf16x8 hfr = *(const bf16x8*)&hC[n0 + g * 8];
        #pragma unroll
        for (int ms = 0; ms < 4; ms++) {
            int mrow = ms * 16 + lr;
            unsigned rd = (unsigned)((mrow * 64 + g * 16) ^ ((mrow & 7) << 4));
            bf16x8 pfr = *(const bf16x8*)(base + rd);
            acc[ms] = __builtin_amdgcn_mfma_f32_16x16x32_bf16(hfr, pfr, acc[ms], 0, 0, 0);
        }
        // next iteration writes the other P buffer; single barrier per chunk is safe
    }

    // ---- store O tile: rows c = w*16 + 4g + r, cols m = m_blk + ms*16 + lr
    #pragma unroll
    for (int ms = 0; ms < 4; ms++) {
        #pragma unroll
        for (int r = 0; r < 4; r++) {
            o[((size_t)b * NC + w * 16 + 4 * g + r) * NN + m_blk + ms * 16 + lr] = acc[ms][r];
        }
    }
}

// ---------------------------------------------------------------------------
// K4: final projection, IN PLACE on d_out viewed as [32768][128] fp32.
// ---------------------------------------------------------------------------
__global__ __launch_bounds__(256) void k_vproj(
    float* __restrict__ o, const float* __restrict__ Wv, const float* __restrict__ bv)
{
    __shared__ __align__(16) float ast[32 * 32];
    __shared__ __align__(16) float bs [32 * 128];

    const int tid = threadIdx.x;
    const int tx = tid & 31, ty = tid >> 5;
    const int r0 = blockIdx.x * 32;

    float acc[4][4] = {};

    for (int cc = 0; cc < 128; cc += 32) {
        __syncthreads();
        {
            int r = tid >> 3, c4 = tid & 7;
            float4 v = *(const float4*)&o[(size_t)(r0 + r) * NC + cc + c4 * 4];
            ast[(c4 * 4 + 0) * 32 + r] = v.x;
            ast[(c4 * 4 + 1) * 32 + r] = v.y;
            ast[(c4 * 4 + 2) * 32 + r] = v.z;
            ast[(c4 * 4 + 3) * 32 + r] = v.w;
        }
        #pragma unroll
        for (int i = 0; i < 4; i++) {
            int idx = tid + i * 256;
            *(float4*)&bs[idx * 4] = *(const float4*)&Wv[(size_t)cc * 128 + idx * 4];
        }
        __syncthreads();
        #pragma unroll
        for (int c = 0; c < 32; c++) {
            float4 a  = *(const float4*)&ast[c * 32 + ty * 4];
            float4 b4 = *(const float4*)&bs [c * 128 + tx * 4];
            acc[0][0] += a.x * b4.x; acc[0][1] += a.x * b4.y; acc[0][2] += a.x * b4.z; acc[0][3] += a.x * b4.w;
            acc[1][0] += a.y * b4.x; acc[1][1] += a.y * b4.y; acc[1][2] += a.y * b4.z; acc[1][3] += a.y * b4.w;
            acc[2][0] += a.z * b4.x; acc[2][1] += a.z * b4.y; acc[2][2] += a.z * b4.z; acc[2][3] += a.z * b4.w;
            acc[3][0] += a.w * b4.x; acc[3][1] += a.w * b4.y; acc[3][2] += a.w * b4.z; acc[3][3] += a.w * b4.w;
        }
    }
    float4 bb = *(const float4*)&bv[tx * 4];
    #pragma unroll
    for (int i = 0; i < 4; i++) {
        float4 r;
        r.x = acc[i][0] + bb.x; r.y = acc[i][1] + bb.y;
        r.z = acc[i][2] + bb.z; r.w = acc[i][3] + bb.w;
        *(float4*)&o[(size_t)(r0 + ty * 4 + i) * NC + tx * 4] = r;
    }
}

// ---------------------------------------------------------------------------
extern "C" void kernel_launch(void* const* d_in, const int* in_sizes, int n_in,
                              void* d_out, int out_size, void* d_ws, size_t ws_size,
                              hipStream_t stream)
{
    const float* x  = (const float*)d_in[0];
    const float* Wf = (const float*)d_in[1];
    const float* bf = (const float*)d_in[2];
    const float* Wg = (const float*)d_in[3];
    const float* bg = (const float*)d_in[4];
    const float* Wh = (const float*)d_in[5];
    const float* bh = (const float*)d_in[6];
    const float* Wv = (const float*)d_in[7];
    const float* bv = (const float*)d_in[8];
    float* out = (float*)d_out;

    // workspace: fb, gb (bf16 [B*N][C]), htb (bf16 [B][C][N]), stat (float2 [B*N])
    unsigned short* fbp = (unsigned short*)d_ws;
    unsigned short* gbp = fbp + (size_t)NB * NN * NC;
    unsigned short* htp = gbp + (size_t)NB * NN * NC;
    float2* stat = (float2*)(htp + (size_t)NB * NN * NC);

    // 1) projections -> bf16 (h transposed)
    k_proj<<<dim3(1024, 1, 3), 256, 0, stream>>>(x, Wf, bf, Wg, bg, Wh, bh, fbp, gbp, htp);

    // 2) softmax row stats (MFMA recompute of S)
    k_stats<<<dim3(NN / 64, NB), 256, 0, stream>>>(fbp, gbp, stat);

    // 3) attention output O staged [B,C,N] in d_out (MFMA S recompute + PV)
    k_out<<<dim3(NN / 64, NB), 512, 0, stream>>>(fbp, gbp, htp, stat, out);

    // 4) final projection in place (implements the [B,C,N]->[B,N,C] flat reshape)
    k_vproj<<<dim3(1024), 256, 0, stream>>>(out, Wv, bv);
}

// Round 4
// 446.081 us; speedup vs baseline: 2.8593x; 1.3866x over previous
//
#include <hip/hip_runtime.h>
#include <math.h>

#define NB 8
#define NN 4096   // pixels per batch
#define NC 128    // channels

typedef __attribute__((ext_vector_type(8)))  short bf16x8;
typedef __attribute__((ext_vector_type(4)))  float f32x4;
typedef __attribute__((ext_vector_type(16))) float f32x16;

#define L2E   1.4426950408889634f
#define SBIAS 43.2808512266689f   /* 30 * log2(e) */

static __device__ __forceinline__ float fexp2(float x) { return __builtin_amdgcn_exp2f(x); }
static __device__ __forceinline__ float flog2(float x) { return __builtin_amdgcn_logf(x); }

static __device__ __forceinline__ unsigned short f2bf(float f) {
    unsigned u = __builtin_bit_cast(unsigned, f);
    return (unsigned short)((u + 0x7FFFu + ((u >> 16) & 1u)) >> 16);
}

// ---------------------------------------------------------------------------
// K1: projections f,g,h (fp32 compute, bf16 outputs).
// f,g: [B*N][C] bf16 row-major.  h: TRANSPOSED ht[B][C][N] bf16.
// ---------------------------------------------------------------------------
__global__ __launch_bounds__(256) void k_proj(
    const float* __restrict__ x,
    const float* __restrict__ Wf, const float* __restrict__ bf,
    const float* __restrict__ Wg, const float* __restrict__ bg,
    const float* __restrict__ Wh, const float* __restrict__ bh,
    unsigned short* __restrict__ fb, unsigned short* __restrict__ gb,
    unsigned short* __restrict__ htb)
{
    const float* W; const float* bias;
    if (blockIdx.z == 0)      { W = Wf; bias = bf; }
    else if (blockIdx.z == 1) { W = Wg; bias = bg; }
    else                      { W = Wh; bias = bh; }

    __shared__ __align__(16) float ast[32 * 32];    // [c][r]
    __shared__ __align__(16) float bs [32 * 128];   // [c][d]

    const int tid = threadIdx.x;
    const int tx = tid & 31, ty = tid >> 5;
    const int r0 = blockIdx.x * 32;

    float acc[4][4] = {};

    for (int cc = 0; cc < 128; cc += 32) {
        __syncthreads();
        {   // stage A (transpose): 1024 floats
            int r = tid >> 3, c4 = tid & 7;
            float4 v = *(const float4*)&x[(size_t)(r0 + r) * NC + cc + c4 * 4];
            ast[(c4 * 4 + 0) * 32 + r] = v.x;
            ast[(c4 * 4 + 1) * 32 + r] = v.y;
            ast[(c4 * 4 + 2) * 32 + r] = v.z;
            ast[(c4 * 4 + 3) * 32 + r] = v.w;
        }
        #pragma unroll
        for (int i = 0; i < 4; i++) {
            int idx = tid + i * 256;
            *(float4*)&bs[idx * 4] = *(const float4*)&W[(size_t)cc * 128 + idx * 4];
        }
        __syncthreads();
        #pragma unroll
        for (int c = 0; c < 32; c++) {
            float4 a  = *(const float4*)&ast[c * 32 + ty * 4];
            float4 b4 = *(const float4*)&bs [c * 128 + tx * 4];
            acc[0][0] += a.x * b4.x; acc[0][1] += a.x * b4.y; acc[0][2] += a.x * b4.z; acc[0][3] += a.x * b4.w;
            acc[1][0] += a.y * b4.x; acc[1][1] += a.y * b4.y; acc[1][2] += a.y * b4.z; acc[1][3] += a.y * b4.w;
            acc[2][0] += a.z * b4.x; acc[2][1] += a.z * b4.y; acc[2][2] += a.z * b4.z; acc[2][3] += a.z * b4.w;
            acc[3][0] += a.w * b4.x; acc[3][1] += a.w * b4.y; acc[3][2] += a.w * b4.z; acc[3][3] += a.w * b4.w;
        }
    }

    float4 bb = *(const float4*)&bias[tx * 4];
    float bbv[4] = { bb.x, bb.y, bb.z, bb.w };

    if (blockIdx.z < 2) {
        unsigned short* out = (blockIdx.z == 0) ? fb : gb;
        #pragma unroll
        for (int i = 0; i < 4; i++) {
            ushort4 v;
            v.x = f2bf(acc[i][0] + bbv[0]);
            v.y = f2bf(acc[i][1] + bbv[1]);
            v.z = f2bf(acc[i][2] + bbv[2]);
            v.w = f2bf(acc[i][3] + bbv[3]);
            *(ushort4*)&out[(size_t)(r0 + ty * 4 + i) * NC + tx * 4] = v;
        }
    } else {
        // h transposed: ht[b][c][n]
        const int b = r0 >> 12;
        const int n0 = (r0 & (NN - 1)) + ty * 4;
        #pragma unroll
        for (int j = 0; j < 4; j++) {
            int c = tx * 4 + j;
            ushort4 v;
            v.x = f2bf(acc[0][j] + bbv[j]);
            v.y = f2bf(acc[1][j] + bbv[j]);
            v.z = f2bf(acc[2][j] + bbv[j]);
            v.w = f2bf(acc[3][j] + bbv[j]);
            *(ushort4*)&htb[((size_t)b * NC + c) * NN + n0] = v;
        }
    }
}

// ---------------------------------------------------------------------------
// K2: softmax normalizer C[n] = -(SBIAS + log2(sum_m exp(S-30))) via 32x32 MFMA.
// Swapped operands: mfma(A=gx rows m, B=fx rows n) -> D[m][n], col=lane&31 = n.
// Block 512 = 8 waves: wave = (n-tile 0..3, m-half 0..1). No max tracking.
// ---------------------------------------------------------------------------
__global__ __launch_bounds__(512, 4) void k_stats(
    const unsigned short* __restrict__ fb, const unsigned short* __restrict__ gb,
    float* __restrict__ Cout)
{
    const int b = blockIdx.y;
    const int w = threadIdx.x >> 6;
    const int l = threadIdx.x & 63;
    const int lr = l & 31, hi = l >> 5;
    const int t = w & 3, half = w >> 2;
    const int nbase = blockIdx.x * 128 + t * 32;

    // hoist B-frags: fx rows nbase+lr, k = 16*kc + 8*hi + j
    const unsigned short* fRow = fb + ((size_t)b * NN + nbase + lr) * NC;
    bf16x8 bfr[8];
    #pragma unroll
    for (int kc = 0; kc < 8; kc++)
        bfr[kc] = *(const bf16x8*)&fRow[kc * 16 + hi * 8];

    const unsigned short* gB = gb + ((size_t)b * NN + (size_t)half * 2048) * NC;

    float sum = 0.f;
    for (int mt = 0; mt < 64; mt++) {
        const unsigned short* gRow = gB + (size_t)(mt * 32 + lr) * NC;
        f32x16 S0 = {}; f32x16 S1 = {};
        #pragma unroll
        for (int kc = 0; kc < 8; kc += 2) {
            S0 = __builtin_amdgcn_mfma_f32_32x32x16_bf16(*(const bf16x8*)&gRow[kc * 16 + hi * 8], bfr[kc], S0, 0, 0, 0);
            S1 = __builtin_amdgcn_mfma_f32_32x32x16_bf16(*(const bf16x8*)&gRow[(kc + 1) * 16 + hi * 8], bfr[kc + 1], S1, 0, 0, 0);
        }
        #pragma unroll
        for (int r = 0; r < 16; r++)
            sum += fexp2(__builtin_fmaf(S0[r] + S1[r], L2E, -SBIAS));
    }

    // lanes l and l^32 hold the same n (col), different m rows: combine
    sum += __shfl_xor(sum, 32, 64);

    __shared__ float lds[128];
    if (half == 1 && l < 32) lds[t * 32 + l] = sum;
    __syncthreads();
    if (half == 0 && l < 32) {
        float tot = sum + lds[t * 32 + l];
        Cout[(size_t)b * NN + nbase + l] = -(SBIAS + flog2(tot));
    }
}

// ---------------------------------------------------------------------------
// K3: O[b][c][m] = sum_n ht[b][c][n] * alpha[n][m]; alpha = exp2(S*L2E + C[n]).
// Unswapped S: mfma(A=fx rows n, B=gx rows m) -> D[n][m], col=lane&31 = m fixed.
// In-register transpose to PV B-frag via cvt_pk_bf16 + shfl_xor(32) + select.
// PV: mfma(A=ht rows c, B=alpha^T rows m). 8 waves: distinct 32-m each,
// full 128-c each. ZERO LDS, ZERO barriers. Grid: (16 m-blocks, nsplit, 8 b).
// ---------------------------------------------------------------------------
__global__ __launch_bounds__(512, 2) void k_out(
    const unsigned short* __restrict__ fb, const unsigned short* __restrict__ gb,
    const unsigned short* __restrict__ htb, const float* __restrict__ Cn,
    float* __restrict__ O0, float* __restrict__ Od, int nsplit)
{
    const int b = blockIdx.z;
    const int tid = threadIdx.x;
    const int w = tid >> 6, l = tid & 63;
    const int lr = l & 31, hi = l >> 5;
    const int m0 = blockIdx.x * 256 + w * 32;

    const int chunks = (NN / 32) / nsplit;
    const int nstart = blockIdx.y * chunks * 32;
    float* O = (blockIdx.y == nsplit - 1) ? Od : O0;

    // hoist gx B-frags (m fixed per wave): rows m0+lr, k = 16*kc + 8*hi + j
    const unsigned short* gRow = gb + ((size_t)b * NN + m0 + lr) * NC;
    bf16x8 gfr[8];
    #pragma unroll
    for (int kc = 0; kc < 8; kc++)
        gfr[kc] = *(const bf16x8*)&gRow[kc * 16 + hi * 8];

    const unsigned short* fB  = fb + (size_t)b * NN * NC;
    const unsigned short* htB = htb + (size_t)b * NC * NN;
    const float* Cb = Cn + (size_t)b * NN;

    f32x16 acc[4] = { {}, {}, {}, {} };

    for (int nc = 0; nc < chunks; nc++) {
        const int n0 = nstart + nc * 32;

        // ---- S tile 32n x 32m, K=128
        const unsigned short* fRow = fB + (size_t)(n0 + lr) * NC;
        f32x16 S0 = {}; f32x16 S1 = {};
        #pragma unroll
        for (int kc = 0; kc < 8; kc += 2) {
            S0 = __builtin_amdgcn_mfma_f32_32x32x16_bf16(*(const bf16x8*)&fRow[kc * 16 + hi * 8], gfr[kc], S0, 0, 0, 0);
            S1 = __builtin_amdgcn_mfma_f32_32x32x16_bf16(*(const bf16x8*)&fRow[(kc + 1) * 16 + hi * 8], gfr[kc + 1], S1, 0, 0, 0);
        }

        // ---- alpha = exp2(S*L2E + C[n]); reg r -> n-off = (r&3)+8*(r>>2)+4*hi
        float4 Cv[4];
        #pragma unroll
        for (int q = 0; q < 4; q++)
            Cv[q] = *(const float4*)&Cb[n0 + q * 8 + hi * 4];

        unsigned pk[8];
        #pragma unroll
        for (int p = 0; p < 8; p++) {
            int r0i = 2 * p, r1i = 2 * p + 1;
            float a0 = fexp2(__builtin_fmaf(S0[r0i] + S1[r0i], L2E, Cv[r0i >> 2][r0i & 3]));
            float a1 = fexp2(__builtin_fmaf(S0[r1i] + S1[r1i], L2E, Cv[r1i >> 2][r1i & 3]));
            asm("v_cvt_pk_bf16_f32 %0, %1, %2" : "=v"(pk[p]) : "v"(a0), "v"(a1));
        }
        unsigned part[8];
        #pragma unroll
        for (int p = 0; p < 8; p++)
            part[p] = (unsigned)__shfl_xor((int)pk[p], 32, 64);

        // ---- assemble PV B-frags (alpha^T rows m, k = n-offset 8*hi+j)
        uint4 b0, b1;
        b0.x = hi ? part[2] : pk[0];
        b0.y = hi ? part[3] : pk[1];
        b0.z = hi ? pk[2]   : part[0];
        b0.w = hi ? pk[3]   : part[1];
        b1.x = hi ? part[6] : pk[4];
        b1.y = hi ? part[7] : pk[5];
        b1.z = hi ? pk[6]   : part[4];
        b1.w = hi ? pk[7]   : part[5];
        bf16x8 B0 = __builtin_bit_cast(bf16x8, b0);
        bf16x8 B1 = __builtin_bit_cast(bf16x8, b1);

        // ---- PV: acc[cb] += ht[cb*32+row][n-chunk] * alpha^T
        #pragma unroll
        for (int cb = 0; cb < 4; cb++) {
            const unsigned short* hRow = htB + (size_t)(cb * 32 + lr) * NN + n0;
            bf16x8 A0 = *(const bf16x8*)&hRow[hi * 8];
            bf16x8 A1 = *(const bf16x8*)&hRow[16 + hi * 8];
            acc[cb] = __builtin_amdgcn_mfma_f32_32x32x16_bf16(A0, B0, acc[cb], 0, 0, 0);
            acc[cb] = __builtin_amdgcn_mfma_f32_32x32x16_bf16(A1, B1, acc[cb], 0, 0, 0);
        }
    }

    // ---- store: O[c = cb*32 + (reg&3)+8*(reg>>2)+4*hi][m = m0+lr]
    #pragma unroll
    for (int cb = 0; cb < 4; cb++) {
        #pragma unroll
        for (int r = 0; r < 16; r++) {
            int row = (r & 3) + 8 * (r >> 2) + 4 * hi;
            O[((size_t)b * NC + cb * 32 + row) * NN + m0 + lr] = acc[cb][r];
        }
    }
}

// ---------------------------------------------------------------------------
// K4: final projection, IN PLACE on d_out viewed as [32768][128] fp32,
// summing the two n-half partial O buffers (d_out-resident + O0 in ws).
// ---------------------------------------------------------------------------
__global__ __launch_bounds__(256) void k_vproj(
    float* __restrict__ o, const float* __restrict__ O0,
    const float* __restrict__ Wv, const float* __restrict__ bv, int has_o0)
{
    __shared__ __align__(16) float ast[32 * 32];
    __shared__ __align__(16) float bs [32 * 128];

    const int tid = threadIdx.x;
    const int tx = tid & 31, ty = tid >> 5;
    const int r0 = blockIdx.x * 32;

    float acc[4][4] = {};

    for (int cc = 0; cc < 128; cc += 32) {
        __syncthreads();
        {
            int r = tid >> 3, c4 = tid & 7;
            size_t idx = (size_t)(r0 + r) * NC + cc + c4 * 4;
            float4 v = *(const float4*)&o[idx];
            if (has_o0) {
                float4 u = *(const float4*)&O0[idx];
                v.x += u.x; v.y += u.y; v.z += u.z; v.w += u.w;
            }
            ast[(c4 * 4 + 0) * 32 + r] = v.x;
            ast[(c4 * 4 + 1) * 32 + r] = v.y;
            ast[(c4 * 4 + 2) * 32 + r] = v.z;
            ast[(c4 * 4 + 3) * 32 + r] = v.w;
        }
        #pragma unroll
        for (int i = 0; i < 4; i++) {
            int idx = tid + i * 256;
            *(float4*)&bs[idx * 4] = *(const float4*)&Wv[(size_t)cc * 128 + idx * 4];
        }
        __syncthreads();
        #pragma unroll
        for (int c = 0; c < 32; c++) {
            float4 a  = *(const float4*)&ast[c * 32 + ty * 4];
            float4 b4 = *(const float4*)&bs [c * 128 + tx * 4];
            acc[0][0] += a.x * b4.x; acc[0][1] += a.x * b4.y; acc[0][2] += a.x * b4.z; acc[0][3] += a.x * b4.w;
            acc[1][0] += a.y * b4.x; acc[1][1] += a.y * b4.y; acc[1][2] += a.y * b4.z; acc[1][3] += a.y * b4.w;
            acc[2][0] += a.z * b4.x; acc[2][1] += a.z * b4.y; acc[2][2] += a.z * b4.z; acc[2][3] += a.z * b4.w;
            acc[3][0] += a.w * b4.x; acc[3][1] += a.w * b4.y; acc[3][2] += a.w * b4.z; acc[3][3] += a.w * b4.w;
        }
    }
    float4 bb = *(const float4*)&bv[tx * 4];
    #pragma unroll
    for (int i = 0; i < 4; i++) {
        float4 r;
        r.x = acc[i][0] + bb.x; r.y = acc[i][1] + bb.y;
        r.z = acc[i][2] + bb.z; r.w = acc[i][3] + bb.w;
        *(float4*)&o[(size_t)(r0 + ty * 4 + i) * NC + tx * 4] = r;
    }
}

// ---------------------------------------------------------------------------
extern "C" void kernel_launch(void* const* d_in, const int* in_sizes, int n_in,
                              void* d_out, int out_size, void* d_ws, size_t ws_size,
                              hipStream_t stream)
{
    const float* x  = (const float*)d_in[0];
    const float* Wf = (const float*)d_in[1];
    const float* bf = (const float*)d_in[2];
    const float* Wg = (const float*)d_in[3];
    const float* bg = (const float*)d_in[4];
    const float* Wh = (const float*)d_in[5];
    const float* bh = (const float*)d_in[6];
    const float* Wv = (const float*)d_in[7];
    const float* bv = (const float*)d_in[8];
    float* out = (float*)d_out;

    // ws: fb, gb (bf16 [B*N][C]), htb (bf16 [B][C][N]), Cn (f32 [B*N]), O0 (f32 [B][C][N])
    unsigned short* fbp = (unsigned short*)d_ws;
    unsigned short* gbp = fbp + (size_t)NB * NN * NC;
    unsigned short* htp = gbp + (size_t)NB * NN * NC;
    float* Cn = (float*)(htp + (size_t)NB * NN * NC);
    float* O0 = Cn + (size_t)NB * NN;
    size_t need = (size_t)((char*)(O0 + (size_t)NB * NC * NN) - (char*)d_ws);
    int nsplit = (ws_size >= need) ? 2 : 1;   // fall back to 1 n-half if ws is tight

    // 1) projections -> bf16 (h transposed)
    k_proj<<<dim3(1024, 1, 3), 256, 0, stream>>>(x, Wf, bf, Wg, bg, Wh, bh, fbp, gbp, htp);

    // 2) softmax normalizers C[n]
    k_stats<<<dim3(NN / 128, NB), 512, 0, stream>>>(fbp, gbp, Cn);

    // 3) attention output, O staged [B,C,N]: last n-half into d_out, first into O0
    k_out<<<dim3(NN / 256, nsplit, NB), 512, 0, stream>>>(fbp, gbp, htp, Cn, O0, out, nsplit);

    // 4) final projection in place (implements the [B,C,N]->[B,N,C] flat reshape)
    k_vproj<<<dim3(1024), 256, 0, stream>>>(out, O0, Wv, bv, nsplit - 1);
}

// Round 5
// 430.892 us; speedup vs baseline: 2.9601x; 1.0352x over previous
//
#include <hip/hip_runtime.h>
#include <math.h>

#define NB 8
#define NN 4096   // pixels per batch
#define NC 128    // channels

typedef __attribute__((ext_vector_type(8)))  short bf16x8;
typedef __attribute__((ext_vector_type(4)))  float f32x4;
typedef __attribute__((ext_vector_type(16))) float f32x16;

#define L2E   1.4426950408889634f
#define SBIAS 43.2808512266689f   /* 30 * log2(e) */

static __device__ __forceinline__ float fexp2(float x) { return __builtin_amdgcn_exp2f(x); }
static __device__ __forceinline__ float flog2(float x) { return __builtin_amdgcn_logf(x); }

static __device__ __forceinline__ unsigned short f2bf(float f) {
    unsigned u = __builtin_bit_cast(unsigned, f);
    return (unsigned short)((u + 0x7FFFu + ((u >> 16) & 1u)) >> 16);
}

// ---------------------------------------------------------------------------
// K1: projections f,g,h (fp32 compute, bf16 outputs).
// f,g: [B*N][C] bf16 row-major.  h: TRANSPOSED ht[B][C][N] bf16.
// ---------------------------------------------------------------------------
__global__ __launch_bounds__(256) void k_proj(
    const float* __restrict__ x,
    const float* __restrict__ Wf, const float* __restrict__ bf,
    const float* __restrict__ Wg, const float* __restrict__ bg,
    const float* __restrict__ Wh, const float* __restrict__ bh,
    unsigned short* __restrict__ fb, unsigned short* __restrict__ gb,
    unsigned short* __restrict__ htb)
{
    const float* W; const float* bias;
    if (blockIdx.z == 0)      { W = Wf; bias = bf; }
    else if (blockIdx.z == 1) { W = Wg; bias = bg; }
    else                      { W = Wh; bias = bh; }

    __shared__ __align__(16) float ast[32 * 32];    // [c][r]
    __shared__ __align__(16) float bs [32 * 128];   // [c][d]

    const int tid = threadIdx.x;
    const int tx = tid & 31, ty = tid >> 5;
    const int r0 = blockIdx.x * 32;

    float acc[4][4] = {};

    for (int cc = 0; cc < 128; cc += 32) {
        __syncthreads();
        {   // stage A (transpose): 1024 floats
            int r = tid >> 3, c4 = tid & 7;
            float4 v = *(const float4*)&x[(size_t)(r0 + r) * NC + cc + c4 * 4];
            ast[(c4 * 4 + 0) * 32 + r] = v.x;
            ast[(c4 * 4 + 1) * 32 + r] = v.y;
            ast[(c4 * 4 + 2) * 32 + r] = v.z;
            ast[(c4 * 4 + 3) * 32 + r] = v.w;
        }
        #pragma unroll
        for (int i = 0; i < 4; i++) {
            int idx = tid + i * 256;
            *(float4*)&bs[idx * 4] = *(const float4*)&W[(size_t)cc * 128 + idx * 4];
        }
        __syncthreads();
        #pragma unroll
        for (int c = 0; c < 32; c++) {
            float4 a  = *(const float4*)&ast[c * 32 + ty * 4];
            float4 b4 = *(const float4*)&bs [c * 128 + tx * 4];
            acc[0][0] += a.x * b4.x; acc[0][1] += a.x * b4.y; acc[0][2] += a.x * b4.z; acc[0][3] += a.x * b4.w;
            acc[1][0] += a.y * b4.x; acc[1][1] += a.y * b4.y; acc[1][2] += a.y * b4.z; acc[1][3] += a.y * b4.w;
            acc[2][0] += a.z * b4.x; acc[2][1] += a.z * b4.y; acc[2][2] += a.z * b4.z; acc[2][3] += a.z * b4.w;
            acc[3][0] += a.w * b4.x; acc[3][1] += a.w * b4.y; acc[3][2] += a.w * b4.z; acc[3][3] += a.w * b4.w;
        }
    }

    float4 bb = *(const float4*)&bias[tx * 4];
    float bbv[4] = { bb.x, bb.y, bb.z, bb.w };

    if (blockIdx.z < 2) {
        unsigned short* out = (blockIdx.z == 0) ? fb : gb;
        #pragma unroll
        for (int i = 0; i < 4; i++) {
            ushort4 v;
            v.x = f2bf(acc[i][0] + bbv[0]);
            v.y = f2bf(acc[i][1] + bbv[1]);
            v.z = f2bf(acc[i][2] + bbv[2]);
            v.w = f2bf(acc[i][3] + bbv[3]);
            *(ushort4*)&out[(size_t)(r0 + ty * 4 + i) * NC + tx * 4] = v;
        }
    } else {
        // h transposed: ht[b][c][n]
        const int b = r0 >> 12;
        const int n0 = (r0 & (NN - 1)) + ty * 4;
        #pragma unroll
        for (int j = 0; j < 4; j++) {
            int c = tx * 4 + j;
            ushort4 v;
            v.x = f2bf(acc[0][j] + bbv[j]);
            v.y = f2bf(acc[1][j] + bbv[j]);
            v.z = f2bf(acc[2][j] + bbv[j]);
            v.w = f2bf(acc[3][j] + bbv[j]);
            *(ushort4*)&htb[((size_t)b * NC + c) * NN + n0] = v;
        }
    }
}

// ---------------------------------------------------------------------------
// K2: softmax normalizer C[n] = -(SBIAS + log2(sum_m exp(S-30))) via 32x32 MFMA.
// Swapped operands: mfma(A=gx rows m, B=fx rows n) -> D[m][n], col=lane&31 = n.
// Block 512 = 8 waves: wave = (n-tile 0..3, m-half 0..1). No max tracking.
// Register double-buffer on the gx row fragments (prefetch next m-tile).
// ---------------------------------------------------------------------------
__global__ __launch_bounds__(512, 2) void k_stats(
    const unsigned short* __restrict__ fb, const unsigned short* __restrict__ gb,
    float* __restrict__ Cout)
{
    const int b = blockIdx.y;
    const int w = threadIdx.x >> 6;
    const int l = threadIdx.x & 63;
    const int lr = l & 31, hi = l >> 5;
    const int t = w & 3, half = w >> 2;
    const int nbase = blockIdx.x * 128 + t * 32;

    // hoist B-frags: fx rows nbase+lr, k = 16*kc + 8*hi + j
    const unsigned short* fRow = fb + ((size_t)b * NN + nbase + lr) * NC;
    bf16x8 bfr[8];
    #pragma unroll
    for (int kc = 0; kc < 8; kc++)
        bfr[kc] = *(const bf16x8*)&fRow[kc * 16 + hi * 8];

    const unsigned short* gB = gb + ((size_t)b * NN + (size_t)half * 2048) * NC;

    // preload m-tile 0
    bf16x8 gcur[8];
    {
        const unsigned short* gRow0 = gB + (size_t)lr * NC;
        #pragma unroll
        for (int kc = 0; kc < 8; kc++)
            gcur[kc] = *(const bf16x8*)&gRow0[kc * 16 + hi * 8];
    }

    float sum = 0.f;
    for (int mt = 0; mt < 64; mt++) {
        // prefetch next m-tile's fragments (dummy re-load of last tile at the end)
        const int mtn = (mt + 1 < 64) ? mt + 1 : mt;
        const unsigned short* gRowN = gB + (size_t)(mtn * 32 + lr) * NC;
        bf16x8 gnxt[8];
        #pragma unroll
        for (int kc = 0; kc < 8; kc++)
            gnxt[kc] = *(const bf16x8*)&gRowN[kc * 16 + hi * 8];

        f32x16 S0 = {}; f32x16 S1 = {};
        #pragma unroll
        for (int kc = 0; kc < 8; kc += 2) {
            S0 = __builtin_amdgcn_mfma_f32_32x32x16_bf16(gcur[kc], bfr[kc], S0, 0, 0, 0);
            S1 = __builtin_amdgcn_mfma_f32_32x32x16_bf16(gcur[kc + 1], bfr[kc + 1], S1, 0, 0, 0);
        }
        #pragma unroll
        for (int r = 0; r < 16; r++)
            sum += fexp2(__builtin_fmaf(S0[r] + S1[r], L2E, -SBIAS));

        #pragma unroll
        for (int kc = 0; kc < 8; kc++) gcur[kc] = gnxt[kc];
    }

    // lanes l and l^32 hold the same n (col), different m rows: combine
    sum += __shfl_xor(sum, 32, 64);

    __shared__ float lds[128];
    if (half == 1 && l < 32) lds[t * 32 + l] = sum;
    __syncthreads();
    if (half == 0 && l < 32) {
        float tot = sum + lds[t * 32 + l];
        Cout[(size_t)b * NN + nbase + l] = -(SBIAS + flog2(tot));
    }
}

// ---------------------------------------------------------------------------
// K3: O[b][c][m] = sum_n ht[b][c][n] * alpha[n][m]; alpha = exp2(S*L2E + C[n]).
// Unswapped S: mfma(A=fx rows n, B=gx rows m) -> D[n][m], col=lane&31 = m fixed.
// In-register transpose to PV B-frag via cvt_pk_bf16 + shfl_xor(32) + select.
// PV: mfma(A=ht rows c, B=alpha^T rows m). ZERO LDS, ZERO barriers.
// Pipelining: fx frags double-buffered (prefetch next chunk); ht frags for the
// CURRENT chunk issued before the S phase (consumed ~after S+exp -> hidden).
// ---------------------------------------------------------------------------
__global__ __launch_bounds__(512, 2) void k_out(
    const unsigned short* __restrict__ fb, const unsigned short* __restrict__ gb,
    const unsigned short* __restrict__ htb, const float* __restrict__ Cn,
    float* __restrict__ O0, float* __restrict__ Od, int nsplit)
{
    const int b = blockIdx.z;
    const int tid = threadIdx.x;
    const int w = tid >> 6, l = tid & 63;
    const int lr = l & 31, hi = l >> 5;
    const int m0 = blockIdx.x * 256 + w * 32;

    const int chunks = (NN / 32) / nsplit;
    const int nstart = blockIdx.y * chunks * 32;
    float* O = (blockIdx.y == nsplit - 1) ? Od : O0;

    // hoist gx B-frags (m fixed per wave): rows m0+lr, k = 16*kc + 8*hi + j
    const unsigned short* gRow = gb + ((size_t)b * NN + m0 + lr) * NC;
    bf16x8 gfr[8];
    #pragma unroll
    for (int kc = 0; kc < 8; kc++)
        gfr[kc] = *(const bf16x8*)&gRow[kc * 16 + hi * 8];

    const unsigned short* fB  = fb + (size_t)b * NN * NC;
    const unsigned short* htB = htb + (size_t)b * NC * NN;
    const float* Cb = Cn + (size_t)b * NN;

    f32x16 acc[4] = { {}, {}, {}, {} };

    // preload fx frags for chunk 0
    bf16x8 fcur[8];
    {
        const unsigned short* fRow0 = fB + (size_t)(nstart + lr) * NC;
        #pragma unroll
        for (int kc = 0; kc < 8; kc++)
            fcur[kc] = *(const bf16x8*)&fRow0[kc * 16 + hi * 8];
    }

    for (int nc = 0; nc < chunks; nc++) {
        const int n0 = nstart + nc * 32;
        const int n1 = nstart + ((nc + 1 < chunks) ? (nc + 1) : nc) * 32;

        // ---- prefetch NEXT chunk's fx frags (independent of this chunk)
        bf16x8 fnxt[8];
        {
            const unsigned short* fRowN = fB + (size_t)(n1 + lr) * NC;
            #pragma unroll
            for (int kc = 0; kc < 8; kc++)
                fnxt[kc] = *(const bf16x8*)&fRowN[kc * 16 + hi * 8];
        }
        // ---- issue CURRENT chunk's ht loads now (used after S+exp phase)
        bf16x8 hA[8];
        #pragma unroll
        for (int cb = 0; cb < 4; cb++) {
            const unsigned short* hRow = htB + (size_t)(cb * 32 + lr) * NN + n0;
            hA[2 * cb]     = *(const bf16x8*)&hRow[hi * 8];
            hA[2 * cb + 1] = *(const bf16x8*)&hRow[16 + hi * 8];
        }
        // ---- issue Cn loads (used after S phase)
        float4 Cv[4];
        #pragma unroll
        for (int q = 0; q < 4; q++)
            Cv[q] = *(const float4*)&Cb[n0 + q * 8 + hi * 4];

        // ---- S tile 32n x 32m, K=128
        f32x16 S0 = {}; f32x16 S1 = {};
        #pragma unroll
        for (int kc = 0; kc < 8; kc += 2) {
            S0 = __builtin_amdgcn_mfma_f32_32x32x16_bf16(fcur[kc], gfr[kc], S0, 0, 0, 0);
            S1 = __builtin_amdgcn_mfma_f32_32x32x16_bf16(fcur[kc + 1], gfr[kc + 1], S1, 0, 0, 0);
        }

        // ---- alpha = exp2(S*L2E + C[n]); reg r -> n-off = (r&3)+8*(r>>2)+4*hi
        unsigned pk[8];
        #pragma unroll
        for (int p = 0; p < 8; p++) {
            int r0i = 2 * p, r1i = 2 * p + 1;
            float a0 = fexp2(__builtin_fmaf(S0[r0i] + S1[r0i], L2E, Cv[r0i >> 2][r0i & 3]));
            float a1 = fexp2(__builtin_fmaf(S0[r1i] + S1[r1i], L2E, Cv[r1i >> 2][r1i & 3]));
            asm("v_cvt_pk_bf16_f32 %0, %1, %2" : "=v"(pk[p]) : "v"(a0), "v"(a1));
        }
        unsigned part[8];
        #pragma unroll
        for (int p = 0; p < 8; p++)
            part[p] = (unsigned)__shfl_xor((int)pk[p], 32, 64);

        // ---- assemble PV B-frags (alpha^T rows m, k = n-offset 8*hi+j)
        uint4 b0, b1;
        b0.x = hi ? part[2] : pk[0];
        b0.y = hi ? part[3] : pk[1];
        b0.z = hi ? pk[2]   : part[0];
        b0.w = hi ? pk[3]   : part[1];
        b1.x = hi ? part[6] : pk[4];
        b1.y = hi ? part[7] : pk[5];
        b1.z = hi ? pk[6]   : part[4];
        b1.w = hi ? pk[7]   : part[5];
        bf16x8 B0 = __builtin_bit_cast(bf16x8, b0);
        bf16x8 B1 = __builtin_bit_cast(bf16x8, b1);

        // ---- PV: acc[cb] += ht[cb*32+row][n-chunk] * alpha^T
        #pragma unroll
        for (int cb = 0; cb < 4; cb++) {
            acc[cb] = __builtin_amdgcn_mfma_f32_32x32x16_bf16(hA[2 * cb],     B0, acc[cb], 0, 0, 0);
            acc[cb] = __builtin_amdgcn_mfma_f32_32x32x16_bf16(hA[2 * cb + 1], B1, acc[cb], 0, 0, 0);
        }

        // ---- rotate prefetch buffer
        #pragma unroll
        for (int kc = 0; kc < 8; kc++) fcur[kc] = fnxt[kc];
    }

    // ---- store: O[c = cb*32 + (reg&3)+8*(reg>>2)+4*hi][m = m0+lr]
    #pragma unroll
    for (int cb = 0; cb < 4; cb++) {
        #pragma unroll
        for (int r = 0; r < 16; r++) {
            int row = (r & 3) + 8 * (r >> 2) + 4 * hi;
            O[((size_t)b * NC + cb * 32 + row) * NN + m0 + lr] = acc[cb][r];
        }
    }
}

// ---------------------------------------------------------------------------
// K4: final projection, IN PLACE on d_out viewed as [32768][128] fp32,
// summing the two n-half partial O buffers (d_out-resident + O0 in ws).
// ---------------------------------------------------------------------------
__global__ __launch_bounds__(256) void k_vproj(
    float* __restrict__ o, const float* __restrict__ O0,
    const float* __restrict__ Wv, const float* __restrict__ bv, int has_o0)
{
    __shared__ __align__(16) float ast[32 * 32];
    __shared__ __align__(16) float bs [32 * 128];

    const int tid = threadIdx.x;
    const int tx = tid & 31, ty = tid >> 5;
    const int r0 = blockIdx.x * 32;

    float acc[4][4] = {};

    for (int cc = 0; cc < 128; cc += 32) {
        __syncthreads();
        {
            int r = tid >> 3, c4 = tid & 7;
            size_t idx = (size_t)(r0 + r) * NC + cc + c4 * 4;
            float4 v = *(const float4*)&o[idx];
            if (has_o0) {
                float4 u = *(const float4*)&O0[idx];
                v.x += u.x; v.y += u.y; v.z += u.z; v.w += u.w;
            }
            ast[(c4 * 4 + 0) * 32 + r] = v.x;
            ast[(c4 * 4 + 1) * 32 + r] = v.y;
            ast[(c4 * 4 + 2) * 32 + r] = v.z;
            ast[(c4 * 4 + 3) * 32 + r] = v.w;
        }
        #pragma unroll
        for (int i = 0; i < 4; i++) {
            int idx = tid + i * 256;
            *(float4*)&bs[idx * 4] = *(const float4*)&Wv[(size_t)cc * 128 + idx * 4];
        }
        __syncthreads();
        #pragma unroll
        for (int c = 0; c < 32; c++) {
            float4 a  = *(const float4*)&ast[c * 32 + ty * 4];
            float4 b4 = *(const float4*)&bs [c * 128 + tx * 4];
            acc[0][0] += a.x * b4.x; acc[0][1] += a.x * b4.y; acc[0][2] += a.x * b4.z; acc[0][3] += a.x * b4.w;
            acc[1][0] += a.y * b4.x; acc[1][1] += a.y * b4.y; acc[1][2] += a.y * b4.z; acc[1][3] += a.y * b4.w;
            acc[2][0] += a.z * b4.x; acc[2][1] += a.z * b4.y; acc[2][2] += a.z * b4.z; acc[2][3] += a.z * b4.w;
            acc[3][0] += a.w * b4.x; acc[3][1] += a.w * b4.y; acc[3][2] += a.w * b4.z; acc[3][3] += a.w * b4.w;
        }
    }
    float4 bb = *(const float4*)&bv[tx * 4];
    #pragma unroll
    for (int i = 0; i < 4; i++) {
        float4 r;
        r.x = acc[i][0] + bb.x; r.y = acc[i][1] + bb.y;
        r.z = acc[i][2] + bb.z; r.w = acc[i][3] + bb.w;
        *(float4*)&o[(size_t)(r0 + ty * 4 + i) * NC + tx * 4] = r;
    }
}

// ---------------------------------------------------------------------------
extern "C" void kernel_launch(void* const* d_in, const int* in_sizes, int n_in,
                              void* d_out, int out_size, void* d_ws, size_t ws_size,
                              hipStream_t stream)
{
    const float* x  = (const float*)d_in[0];
    const float* Wf = (const float*)d_in[1];
    const float* bf = (const float*)d_in[2];
    const float* Wg = (const float*)d_in[3];
    const float* bg = (const float*)d_in[4];
    const float* Wh = (const float*)d_in[5];
    const float* bh = (const float*)d_in[6];
    const float* Wv = (const float*)d_in[7];
    const float* bv = (const float*)d_in[8];
    float* out = (float*)d_out;

    // ws: fb, gb (bf16 [B*N][C]), htb (bf16 [B][C][N]), Cn (f32 [B*N]), O0 (f32 [B][C][N])
    unsigned short* fbp = (unsigned short*)d_ws;
    unsigned short* gbp = fbp + (size_t)NB * NN * NC;
    unsigned short* htp = gbp + (size_t)NB * NN * NC;
    float* Cn = (float*)(htp + (size_t)NB * NN * NC);
    float* O0 = Cn + (size_t)NB * NN;
    size_t need = (size_t)((char*)(O0 + (size_t)NB * NC * NN) - (char*)d_ws);
    int nsplit = (ws_size >= need) ? 2 : 1;   // fall back to 1 n-half if ws is tight

    // 1) projections -> bf16 (h transposed)
    k_proj<<<dim3(1024, 1, 3), 256, 0, stream>>>(x, Wf, bf, Wg, bg, Wh, bh, fbp, gbp, htp);

    // 2) softmax normalizers C[n]
    k_stats<<<dim3(NN / 128, NB), 512, 0, stream>>>(fbp, gbp, Cn);

    // 3) attention output, O staged [B,C,N]: last n-half into d_out, first into O0
    k_out<<<dim3(NN / 256, nsplit, NB), 512, 0, stream>>>(fbp, gbp, htp, Cn, O0, out, nsplit);

    // 4) final projection in place (implements the [B,C,N]->[B,N,C] flat reshape)
    k_vproj<<<dim3(1024), 256, 0, stream>>>(out, O0, Wv, bv, nsplit - 1);
}